// Round 10
// baseline (430.300 us; speedup 1.0000x reference)
//
#include <hip/hip_runtime.h>

// LengthRegulator: B=64, T=512, D=384, MAX_LEN=4096
// R10 = R5 (verified best: kernel 84us, 419.5 total) with ROWS 64->128.
//   Rationale: only remaining lever that does NOT touch the copy-loop schedule
//   (R9 proved the compiler's tight load->store interleave is optimal; R6/R7
//   proved block-shrink and barrier-removal regress). Halves the number of
//   per-block scan prologues (4096->2048 blocks) and duration-load traffic.
//   Copy loop body/pattern is IDENTICAL to R5 (just ITER 12->24).
// Measured context (R8 diagnostic): timed region = kernel + ~335us harness fill
//   /gaps; R5 traffic is already minimal (403MB write + 22.7MB fetch @ 5.06TB/s).
// Swizzle: blockIdx%8 == b%8 pins each batch's x slice to one XCD's L2.
// Output layout (flat float32): [B*ML*D] out, then [B] mel_len (as float).

#define T_DIM 512
#define D_DIM 384
#define D4    (D_DIM / 4)   // 96 float4 per row
#define ROWS  128           // output rows per block (R5 had 64)
#define BLOCK 512
#define ITER  ((ROWS * D4) / BLOCK)  // 24
#define NWAVE (BLOCK / 64)  // 8

typedef float vfloat4 __attribute__((ext_vector_type(4)));

__global__ __launch_bounds__(BLOCK) void lr_fused_kernel(
    const float* __restrict__ x,         // [B, T, D]
    const int*   __restrict__ duration,  // [B, T]
    float*       __restrict__ out,       // [B, ML, D] + [B] mel tail
    int B, int ML)
{
    __shared__ int s_wsum[NWAVE];
    __shared__ int s_idx[ROWS];

    const int b     = blockIdx.x % B;   // XCD = blockIdx % 8 == b % 8
    const int chunk = blockIdx.x / B;
    const int row0  = chunk * ROWS;
    const int tid   = threadIdx.x;
    const int lane  = tid & 63;
    const int wid   = tid >> 6;

    // ---- inclusive scan of duration[b,:]: wave shfl scan + wave-total fixup ----
    const int d = duration[b * T_DIM + tid];
    int v = d;
    #pragma unroll
    for (int off = 1; off < 64; off <<= 1) {
        int u = __shfl_up(v, off);
        if (lane >= off) v += u;
    }
    if (lane == 63) s_wsum[wid] = v;     // wave totals
    __syncthreads();

    int wprefix = 0, mel = 0;
    #pragma unroll
    for (int w = 0; w < NWAVE; ++w) {
        const int s = s_wsum[w];
        if (w < wid) wprefix += s;
        mel += s;
    }
    const int end   = wprefix + v;       // inclusive csum[tid]
    const int start = end - d;           // csum[tid-1]

    // init window to "masked" (needs tid<128 => two banks of 64; no extra barrier:
    // writes happen before the second __syncthreads below)
    if (tid < ROWS) s_idx[tid] = -1;
    __syncthreads();

    // ---- scatter: token tid owns output rows [start, end); write the overlap
    //      with this block's window [row0, row0+ROWS). <=7 entries/thread. ----
    const int lo = start > row0        ? start : row0;
    const int hi = end < row0 + ROWS   ? end   : row0 + ROWS;
    for (int p = lo; p < hi; ++p) s_idx[p - row0] = tid;
    __syncthreads();

    if (chunk == 0 && tid == 0)
        out[(long long)B * ML * D_DIM + b] = (float)mel;

    // ---- gather copy: 128 rows x 96 float4; body identical to R5 ----
    const vfloat4* __restrict__ x4   = (const vfloat4*)x;
    vfloat4*       __restrict__ out4 = (vfloat4*)out;
    const long long out_base = ((long long)b * ML + row0) * D4;
    const long long x_base   = (long long)b * T_DIM * D4;

    #pragma unroll
    for (int i = 0; i < ITER; ++i) {
        const int flat = tid + i * BLOCK;
        const int r = flat / D4;            // constant divisor -> magic mul
        const int j = flat - r * D4;
        const int t = s_idx[r];             // LDS broadcast
        vfloat4 vv = (vfloat4)(0.f, 0.f, 0.f, 0.f);
        if (t >= 0) vv = x4[x_base + (long long)t * D4 + j];
        out4[out_base + flat] = vv;         // plain store (nt A/B'd out in R2)
    }
}

extern "C" void kernel_launch(void* const* d_in, const int* in_sizes, int n_in,
                              void* d_out, int out_size, void* d_ws, size_t ws_size,
                              hipStream_t stream) {
    const float* x   = (const float*)d_in[0];
    const int*   dur = (const int*)d_in[1];
    float*       out = (float*)d_out;
    (void)d_ws; (void)ws_size;

    const int B  = in_sizes[1] / T_DIM;                 // 64
    const int ML = (out_size - B) / (B * D_DIM);        // 4096

    const int grid = B * (ML / ROWS);                   // 2048 blocks
    hipLaunchKernelGGL(lr_fused_kernel, dim3(grid), dim3(BLOCK), 0, stream,
                       x, dur, out, B, ML);
}